// Round 11
// baseline (405.576 us; speedup 1.0000x reference)
//
#include <hip/hip_runtime.h>
#include <math.h>

#define BGR 32
#define NPER0 1024
#define N0 (BGR * NPER0)
#define FDIM 128
#define EDG 524288
#define EPG (EDG / BGR)
#define K1 512
#define K2 256
#define K3 128
#define EBLK (EDG / 256)  // edge-parallel blocks (2048)
#define SXP 36            // sxT row pad (floats): 16B-aligned b128 reads
#define CAP 64            // slots per node (Poisson(16); P(deg>64) ~ 1e-18)

// Order-preserving float<->uint encoding (radix-select keys).
__device__ __forceinline__ unsigned enc_f(float v) {
    unsigned u = __float_as_uint(v);
    return (u & 0x80000000u) ? ~u : (u | 0x80000000u);
}

// ---------------------------------------------------------------------------
// Zero the three degree-counter arrays (binned later via atomics).
// ---------------------------------------------------------------------------
__global__ void zero_all(int* __restrict__ cntA, int* __restrict__ cntB,
                         int* __restrict__ cntC) {
    int i = blockIdx.x * 256 + threadIdx.x;
    if (i < N0) cntA[i] = 0;
    if (i < BGR * K1) cntB[i] = 0;
    if (i < BGR * K2) cntC[i] = 0;
}

// ---------------------------------------------------------------------------
// Register-tiled projection compute (shared by both load variants):
// 32 nodes x 128 features per tile; thread=(feature-quad, node-quad);
// 4x4 outer product, 2 x ds_read_b128 per k-step.
// ---------------------------------------------------------------------------
__device__ __forceinline__ void proj_compute(float* __restrict__ hp, int nb, int t,
                                             const float* __restrict__ sW,
                                             const float* __restrict__ sxT) {
    const int fg = t >> 3, ng = t & 7, h = fg >> 3;
    const float* ap = sxT + h * 32 * SXP + ng * 4;
    const float* bp = sW + h * 1024 + (fg & 7) * 4;
    float4 acc0 = {0.f, 0.f, 0.f, 0.f}, acc1 = acc0, acc2 = acc0, acc3 = acc0;
#pragma unroll
    for (int k = 0; k < 32; k++) {
        float4 a = *(const float4*)(ap + k * SXP);
        float4 b = *(const float4*)(bp + k * 32);
        acc0.x = fmaf(a.x, b.x, acc0.x); acc0.y = fmaf(a.x, b.y, acc0.y);
        acc0.z = fmaf(a.x, b.z, acc0.z); acc0.w = fmaf(a.x, b.w, acc0.w);
        acc1.x = fmaf(a.y, b.x, acc1.x); acc1.y = fmaf(a.y, b.y, acc1.y);
        acc1.z = fmaf(a.y, b.z, acc1.z); acc1.w = fmaf(a.y, b.w, acc1.w);
        acc2.x = fmaf(a.z, b.x, acc2.x); acc2.y = fmaf(a.z, b.y, acc2.y);
        acc2.z = fmaf(a.z, b.z, acc2.z); acc2.w = fmaf(a.z, b.w, acc2.w);
        acc3.x = fmaf(a.w, b.x, acc3.x); acc3.y = fmaf(a.w, b.y, acc3.y);
        acc3.z = fmaf(a.w, b.z, acc3.z); acc3.w = fmaf(a.w, b.w, acc3.w);
    }
    float4* op = (float4*)(hp + (size_t)(nb + ng * 4) * FDIM + fg * 4);
    op[0] = acc0; op[32] = acc1; op[64] = acc2; op[96] = acc3;
}

// ---------------------------------------------------------------------------
// Fat kernel (stage 1): direct edge binning (blocks < EBLK) | proj1.
// ---------------------------------------------------------------------------
__global__ void bin_proj1(const int* __restrict__ src, const int* __restrict__ dst,
                          int* __restrict__ cnt, int* __restrict__ slot,
                          const float* __restrict__ x, const float* __restrict__ W,
                          float* __restrict__ hp) {
    __shared__ __align__(16) float sW[4096];
    __shared__ __align__(16) float sxT[128 * SXP];
    const int t = threadIdx.x;
    if (blockIdx.x < EBLK) {
        int e = blockIdx.x * 256 + t;
        int s = src[e];
        int d = dst[e];
        int p = atomicAdd(&cnt[d], 1);
        if (p < CAP) slot[d * CAP + p] = s;
        return;
    }
    const int nb = (blockIdx.x - EBLK) * 32;
    for (int i = t; i < 4096; i += 256) sW[i] = W[i];
    for (int i = t; i < 4096; i += 256) {
        int node = i >> 7, dim = i & 127;
        sxT[dim * SXP + node] = x[(size_t)(nb + node) * FDIM + dim];
    }
    __syncthreads();
    proj_compute(hp, nb, t, sW, sxT);
}

// ---------------------------------------------------------------------------
// Fat kernel (stages 2/3): edge remap+binning over ORIGINAL edges with
// (composed) nmap (blocks < EBLK) | projection with perm-gathered input
// xn-row = hact[perm[newid]] * mult[newid] (xn never materialized).
// nmapB == nullptr -> stage 2 (single map); else compose nmapA then nmapB.
// ---------------------------------------------------------------------------
__global__ void bin_proj23(const int* __restrict__ src0, const int* __restrict__ dst0,
                           const int* __restrict__ nmapA, const int* __restrict__ nmapB,
                           int* __restrict__ cnt_next, int* __restrict__ slot_next,
                           const float* __restrict__ ha, const int* __restrict__ perm,
                           const float* __restrict__ mult, const float* __restrict__ W,
                           float* __restrict__ hp) {
    __shared__ __align__(16) float sW[4096];
    __shared__ __align__(16) float sxT[128 * SXP];
    const int t = threadIdx.x;
    if (blockIdx.x < EBLK) {
        int e = blockIdx.x * 256 + t;
        int a = nmapA[src0[e]];
        int b = nmapA[dst0[e]];
        if (nmapB != nullptr) {  // wave-uniform branch
            a = (a >= 0) ? nmapB[a] : -1;
            b = (b >= 0) ? nmapB[b] : -1;
        }
        if (a >= 0 && b >= 0) {
            int p = atomicAdd(&cnt_next[b], 1);
            if (p < CAP) slot_next[b * CAP + p] = a;
        }
        return;
    }
    const int nb = (blockIdx.x - EBLK) * 32;
    for (int i = t; i < 4096; i += 256) sW[i] = W[i];
    for (int i = t; i < 4096; i += 256) {
        int node = i >> 7, dim = i & 127;
        int newid = nb + node;
        sxT[dim * SXP + node] = ha[(size_t)perm[newid] * FDIM + dim] * mult[newid];
    }
    __syncthreads();
    proj_compute(hp, nb, t, sW, sxT);
}

// ---------------------------------------------------------------------------
// GCN aggregation (gather via slots) + bias + relu + fused attention score.
// Wave per node; lane = 2 features (float2); shfl-broadcast edge prefetch
// (4x unrolled). dinv on the fly from cnt. Graph->XCD swizzle: blk%32.
// ---------------------------------------------------------------------------
__global__ void agg_kernel(const float* __restrict__ hp, const float* __restrict__ b,
                           const int* __restrict__ cnt, const int* __restrict__ slot,
                           const float* __restrict__ A, const float* __restrict__ psW,
                           float* __restrict__ ha, float* __restrict__ cs, int nper) {
    const int w = threadIdx.x >> 6;
    const int lane = threadIdx.x & 63;
    const int g = blockIdx.x & 31;
    const int chunk = blockIdx.x >> 5;
    const int i = g * nper + chunk * 4 + w;
    const int ci = cnt[i];
    const float di = rsqrtf((float)ci + 1.0f);
    const int c = min(ci, CAP);
    const float2* __restrict__ hp2 = (const float2*)hp;
    float2 self = hp2[(size_t)i * 64 + lane];
    float accx = self.x * di * di, accy = self.y * di * di;
    int idx = 0;
    float dv = 0.0f;
    if (lane < c) {
        idx = slot[i * CAP + lane];
        dv = rsqrtf((float)cnt[idx] + 1.0f);
    }
    int j = 0;
    for (; j + 3 < c; j += 4) {
        int s0 = __shfl(idx, j, 64);
        int s1 = __shfl(idx, j + 1, 64);
        int s2 = __shfl(idx, j + 2, 64);
        int s3 = __shfl(idx, j + 3, 64);
        float c0 = __shfl(dv, j, 64) * di;
        float c1 = __shfl(dv, j + 1, 64) * di;
        float c2 = __shfl(dv, j + 2, 64) * di;
        float c3 = __shfl(dv, j + 3, 64) * di;
        float2 v0 = hp2[(size_t)s0 * 64 + lane];
        float2 v1 = hp2[(size_t)s1 * 64 + lane];
        float2 v2 = hp2[(size_t)s2 * 64 + lane];
        float2 v3 = hp2[(size_t)s3 * 64 + lane];
        accx = fmaf(v0.x, c0, accx); accy = fmaf(v0.y, c0, accy);
        accx = fmaf(v1.x, c1, accx); accy = fmaf(v1.y, c1, accy);
        accx = fmaf(v2.x, c2, accx); accy = fmaf(v2.y, c2, accy);
        accx = fmaf(v3.x, c3, accx); accy = fmaf(v3.y, c3, accy);
    }
    for (; j < c; j++) {
        int s = __shfl(idx, j, 64);
        float co = __shfl(dv, j, 64) * di;
        float2 v = hp2[(size_t)s * 64 + lane];
        accx = fmaf(v.x, co, accx); accy = fmaf(v.y, co, accy);
    }
    float2 bb = ((const float2*)b)[lane];
    float2 o;
    o.x = fmaxf(accx + bb.x, 0.0f);
    o.y = fmaxf(accy + bb.y, 0.0f);
    ((float2*)ha)[(size_t)i * 64 + lane] = o;
    float2 Av = ((const float2*)A)[lane];
    float2 Pv = ((const float2*)psW)[lane];
    float a = o.x * Av.x + o.y * Av.y;
    float p = o.x * Pv.x + o.y * Pv.y;
#pragma unroll
    for (int d = 8; d > 0; d >>= 1) {
        a += __shfl_down(a, d, 16);
        p += __shfl_down(p, d, 16);
    }
    float part = a * p;                  // heads at lanes 0,16,32,48
    part += __shfl_down(part, 16, 64);
    part += __shfl_down(part, 32, 64);
    if (lane == 0) cs[i] = part;
}

// ---------------------------------------------------------------------------
// Score-agg + radix top-k SET + FUSED pooling readout. Block g owns graph g:
// after selection, gather hact[perm]·mult and write per-feature max & sum
// slices with plain stores (no atomics, no zero-init needed).
// ---------------------------------------------------------------------------
__global__ void topk_pool(const float* __restrict__ cs, const int* __restrict__ cnt,
                          const int* __restrict__ slot, const float* __restrict__ psb,
                          int nper, int k, int* __restrict__ nmap, int* __restrict__ perm,
                          float* __restrict__ mult, const float* __restrict__ ha,
                          float* __restrict__ rmax, float* __restrict__ rsum) {
    __shared__ float sc[NPER0];
    __shared__ unsigned ukey[NPER0];
    __shared__ unsigned hist[256];
    __shared__ unsigned wtot[4];
    __shared__ unsigned sel[2];
    __shared__ int ctr[2];
    __shared__ int lperm[K1];      // local node idx of kept slot
    __shared__ float lmult[K1];
    __shared__ float pmax[128], psum[128];
    const int g = blockIdx.x, t = threadIdx.x;
    const int w = t >> 6, l = t & 63;
    const int gnb = g * nper;
    const float pb = psb[0];
    for (int i = t; i < nper; i += 256) {
        int node = gnb + i;
        int ci = cnt[node];
        float di = rsqrtf((float)ci + 1.0f);
        float acc = cs[node] * di * di;
        int c = min(ci, CAP);
        for (int j = 0; j < c; j++) {
            int s = slot[node * CAP + j];
            acc = fmaf(cs[s], rsqrtf((float)cnt[s] + 1.0f) * di, acc);
        }
        float v = acc + pb;
        sc[i] = v;
        ukey[i] = enc_f(v);
    }
    if (t == 0) { sel[0] = 0u; sel[1] = (unsigned)k; }
    __syncthreads();
    for (int shift = 24; shift >= 0; shift -= 8) {
        hist[t] = 0u;
        __syncthreads();
        const unsigned prefix = sel[0];
        const unsigned need = sel[1];
        for (int i = t; i < nper; i += 256) {
            unsigned u = ukey[i];
            if (shift == 24 || (u >> (shift + 8)) == (prefix >> (shift + 8)))
                atomicAdd(&hist[(u >> shift) & 255], 1u);
        }
        __syncthreads();
        const unsigned h = hist[t];
        unsigned s = h;
#pragma unroll
        for (int off = 1; off < 64; off <<= 1) {
            unsigned v = __shfl_down(s, off, 64);
            if (l + off < 64) s += v;
        }
        if (l == 0) wtot[w] = s;
        __syncthreads();
        unsigned add = 0;
        for (int ww = w + 1; ww < 4; ww++) add += wtot[ww];
        const unsigned sfx = s + add;   // #keys with digit >= t (within prefix)
        const unsigned gtr = sfx - h;   // #keys with digit >  t
        if (sfx >= need && gtr < need) {  // exactly one thread
            sel[0] = prefix | ((unsigned)t << shift);
            sel[1] = need - gtr;
        }
        __syncthreads();
    }
    const unsigned T = sel[0];
    const int need = (int)sel[1];
    if (t == 0) { ctr[0] = 0; ctr[1] = k - need; }
    __syncthreads();
    for (int i = t; i < nper; i += 256) {
        unsigned u = ukey[i];
        int node = gnb + i;
        int newid = -1;
        if (u > T) {
            newid = atomicAdd(&ctr[0], 1);
        } else if (u == T) {
            int slot2 = atomicAdd(&ctr[1], 1);
            if (slot2 >= k) slot2 = -1;
            newid = slot2;
        }
        nmap[node] = (newid >= 0) ? g * k + newid : -1;
        if (newid >= 0) {
            float m = tanhf(sc[i]);
            perm[g * k + newid] = node;
            mult[g * k + newid] = m;
            lperm[newid] = i;
            lmult[newid] = m;
        }
    }
    __syncthreads();
    // fused pooling readout (graph-local, plain stores)
    const int f = t & 127, half = t >> 7;
    float vmax = -1e30f, vsum = 0.0f;
    for (int j = half; j < k; j += 2) {
        float v = ha[(size_t)(gnb + lperm[j]) * FDIM + f] * lmult[j];
        vmax = fmaxf(vmax, v);
        vsum += v;
    }
    if (half) { pmax[f] = vmax; psum[f] = vsum; }
    __syncthreads();
    if (!half) {
        rmax[g * FDIM + f] = fmaxf(vmax, pmax[f]);
        rsum[g * FDIM + f] = vsum + psum[f];
    }
}

// ---------------------------------------------------------------------------
// Final MLP + log_softmax. One block per graph, 128 threads.
// ---------------------------------------------------------------------------
__global__ void final_mlp(const float* __restrict__ rmax, const float* __restrict__ rsum,
                          const float* __restrict__ l1W, const float* __restrict__ l1b,
                          const float* __restrict__ l2W, const float* __restrict__ l2b,
                          const float* __restrict__ l3W, const float* __restrict__ l3b,
                          float* __restrict__ out) {
    __shared__ float sz[256], s1[128], s2[64], s3[10], red[2];
    const int g = blockIdx.x, t = threadIdx.x;
    const int RS = BGR * FDIM;
    sz[t] = rmax[g * FDIM + t] + rmax[RS + g * FDIM + t] + rmax[2 * RS + g * FDIM + t];
    sz[t + 128] = rsum[g * FDIM + t] / (float)K1 + rsum[RS + g * FDIM + t] / (float)K2 +
                  rsum[2 * RS + g * FDIM + t] / (float)K3;
    __syncthreads();
    float acc = l1b[t];
    for (int i = 0; i < 256; i++) acc = fmaf(sz[i], l1W[i * 128 + t], acc);
    s1[t] = fmaxf(acc, 0.0f);
    __syncthreads();
    if (t < 64) {
        float a2 = l2b[t];
        for (int i = 0; i < 128; i++) a2 = fmaf(s1[i], l2W[i * 64 + t], a2);
        s2[t] = fmaxf(a2, 0.0f);
    }
    __syncthreads();
    if (t < 10) {
        float a3 = l3b[t];
        for (int i = 0; i < 64; i++) a3 = fmaf(s2[i], l3W[i * 10 + t], a3);
        s3[t] = a3;
    }
    __syncthreads();
    if (t == 0) {
        float m = -1e30f;
        for (int c = 0; c < 10; c++) m = fmaxf(m, s3[c]);
        float sum = 0.0f;
        for (int c = 0; c < 10; c++) sum += expf(s3[c] - m);
        red[0] = m;
        red[1] = logf(sum);
    }
    __syncthreads();
    if (t < 10) out[g * 10 + t] = s3[t] - red[0] - red[1];
}

// ---------------------------------------------------------------------------
extern "C" void kernel_launch(void* const* d_in, const int* in_sizes, int n_in,
                              void* d_out, int out_size, void* d_ws, size_t ws_size,
                              hipStream_t stream) {
    const float* x    = (const float*)d_in[0];
    const int* src0   = (const int*)d_in[1];
    const int* dst0   = (const int*)d_in[2];
    const float* W1   = (const float*)d_in[3];
    const float* b1   = (const float*)d_in[4];
    const float* A1   = (const float*)d_in[5];
    const float* ps1W = (const float*)d_in[6];
    const float* ps1b = (const float*)d_in[7];
    const float* W2   = (const float*)d_in[8];
    const float* b2   = (const float*)d_in[9];
    const float* A2   = (const float*)d_in[10];
    const float* ps2W = (const float*)d_in[11];
    const float* ps2b = (const float*)d_in[12];
    const float* W3   = (const float*)d_in[13];
    const float* b3   = (const float*)d_in[14];
    const float* A3   = (const float*)d_in[15];
    const float* ps3W = (const float*)d_in[16];
    const float* ps3b = (const float*)d_in[17];
    const float* l1W  = (const float*)d_in[18];
    const float* l1b  = (const float*)d_in[19];
    const float* l2W  = (const float*)d_in[20];
    const float* l2b  = (const float*)d_in[21];
    const float* l3W  = (const float*)d_in[22];
    const float* l3b  = (const float*)d_in[23];
    float* out = (float*)d_out;

    char* ws = (char*)d_ws;
    size_t o = 0;
    auto alloc = [&](size_t bytes) -> void* {
        void* p = ws + o;
        o += (bytes + 255) & ~(size_t)255;
        return p;
    };
    float* hproj = (float*)alloc((size_t)N0 * FDIM * 4);
    float* hact  = (float*)alloc((size_t)N0 * FDIM * 4);
    int*   cntA  = (int*)alloc(N0 * 4);
    int*   cntB  = (int*)alloc(BGR * K1 * 4);
    int*   cntC  = (int*)alloc(BGR * K2 * 4);
    int*   slotA = (int*)alloc((size_t)N0 * CAP * 4);
    int*   slotB = (int*)alloc((size_t)BGR * K1 * CAP * 4);
    int*   slotC = (int*)alloc((size_t)BGR * K2 * CAP * 4);
    float* cs    = (float*)alloc(N0 * 4);
    int*   nmapA = (int*)alloc(N0 * 4);
    int*   nmapB = (int*)alloc(BGR * K1 * 4);
    int*   nmapC = (int*)alloc(BGR * K2 * 4);
    int*   perm  = (int*)alloc(BGR * K1 * 4);
    float* mult  = (float*)alloc(BGR * K1 * 4);
    float* rmax  = (float*)alloc(3 * BGR * FDIM * 4);
    float* rsum  = (float*)alloc(3 * BGR * FDIM * 4);

    const int n1 = BGR * K1, n2 = BGR * K2;
    const int RS = BGR * FDIM;

    // ---------------- Stage 1: n=32768, nper=1024, k=512 ----------------
    zero_all<<<N0 / 256, 256, 0, stream>>>(cntA, cntB, cntC);
    bin_proj1<<<EBLK + N0 / 32, 256, 0, stream>>>(src0, dst0, cntA, slotA, x, W1, hproj);
    agg_kernel<<<N0 / 4, 256, 0, stream>>>(hproj, b1, cntA, slotA, A1, ps1W, hact, cs, NPER0);
    topk_pool<<<BGR, 256, 0, stream>>>(cs, cntA, slotA, ps1b, NPER0, K1,
                                       nmapA, perm, mult, hact, rmax, rsum);

    // ---------------- Stage 2: n=16384, nper=512, k=256 ----------------
    bin_proj23<<<EBLK + n1 / 32, 256, 0, stream>>>(src0, dst0, nmapA, nullptr,
                                                   cntB, slotB, hact, perm, mult, W2, hproj);
    agg_kernel<<<n1 / 4, 256, 0, stream>>>(hproj, b2, cntB, slotB, A2, ps2W, hact, cs, K1);
    topk_pool<<<BGR, 256, 0, stream>>>(cs, cntB, slotB, ps2b, K1, K2,
                                       nmapB, perm, mult, hact, rmax + RS, rsum + RS);

    // ---------------- Stage 3: n=8192, nper=256, k=128 ----------------
    bin_proj23<<<EBLK + n2 / 32, 256, 0, stream>>>(src0, dst0, nmapA, nmapB,
                                                   cntC, slotC, hact, perm, mult, W3, hproj);
    agg_kernel<<<n2 / 4, 256, 0, stream>>>(hproj, b3, cntC, slotC, A3, ps3W, hact, cs, K2);
    topk_pool<<<BGR, 256, 0, stream>>>(cs, cntC, slotC, ps3b, K2, K3,
                                       nmapC, perm, mult, hact, rmax + 2 * RS, rsum + 2 * RS);

    // ---------------- Final MLP ----------------
    final_mlp<<<BGR, 128, 0, stream>>>(rmax, rsum, l1W, l1b, l2W, l2b, l3W, l3b, out);

    (void)in_sizes; (void)n_in; (void)out_size; (void)ws_size;
}

// Round 12
// 279.928 us; speedup vs baseline: 1.4489x; 1.4489x over previous
//
#include <hip/hip_runtime.h>
#include <math.h>

#define BGR 32
#define NPER0 1024
#define N0 (BGR * NPER0)
#define FDIM 128
#define EDG 524288
#define K1 512
#define K2 256
#define K3 128
#define EBLK (EDG / 256)  // edge-parallel blocks (2048)
#define SXP 36            // sxT row pad (floats): 16B-aligned b128 reads
#define CAP 64            // slots per node (Poisson(16); P(deg>64) ~ 1e-18)

// Order-preserving float<->uint encoding (radix keys + atomicMax readout).
__device__ __forceinline__ unsigned enc_f(float v) {
    unsigned u = __float_as_uint(v);
    return (u & 0x80000000u) ? ~u : (u | 0x80000000u);
}
__device__ __forceinline__ float dec_f(unsigned u) {
    return (u & 0x80000000u) ? __uint_as_float(u ^ 0x80000000u) : __uint_as_float(~u);
}

// ---------------------------------------------------------------------------
// Zero degree counters + atomic readout accumulators.
// ---------------------------------------------------------------------------
__global__ void zero_all(int* __restrict__ cntA, int* __restrict__ cntB,
                         int* __restrict__ cntC, unsigned* __restrict__ rmax,
                         float* __restrict__ rsum) {
    int i = blockIdx.x * 256 + threadIdx.x;
    if (i < N0) cntA[i] = 0;
    if (i < BGR * K1) cntB[i] = 0;
    if (i < BGR * K2) cntC[i] = 0;
    if (i < 3 * BGR * FDIM) { rmax[i] = 0u; rsum[i] = 0.0f; }
}

// ---------------------------------------------------------------------------
// Register-tiled projection compute: 32 nodes x 128 feats per tile;
// thread=(feature-quad, node-quad); 4x4 outer product, 2 ds_read_b128/k-step.
// ---------------------------------------------------------------------------
__device__ __forceinline__ void proj_compute(float* __restrict__ hp, int nb, int t,
                                             const float* __restrict__ sW,
                                             const float* __restrict__ sxT) {
    const int fg = t >> 3, ng = t & 7, h = fg >> 3;
    const float* ap = sxT + h * 32 * SXP + ng * 4;
    const float* bp = sW + h * 1024 + (fg & 7) * 4;
    float4 acc0 = {0.f, 0.f, 0.f, 0.f}, acc1 = acc0, acc2 = acc0, acc3 = acc0;
#pragma unroll
    for (int k = 0; k < 32; k++) {
        float4 a = *(const float4*)(ap + k * SXP);
        float4 b = *(const float4*)(bp + k * 32);
        acc0.x = fmaf(a.x, b.x, acc0.x); acc0.y = fmaf(a.x, b.y, acc0.y);
        acc0.z = fmaf(a.x, b.z, acc0.z); acc0.w = fmaf(a.x, b.w, acc0.w);
        acc1.x = fmaf(a.y, b.x, acc1.x); acc1.y = fmaf(a.y, b.y, acc1.y);
        acc1.z = fmaf(a.y, b.z, acc1.z); acc1.w = fmaf(a.y, b.w, acc1.w);
        acc2.x = fmaf(a.z, b.x, acc2.x); acc2.y = fmaf(a.z, b.y, acc2.y);
        acc2.z = fmaf(a.z, b.z, acc2.z); acc2.w = fmaf(a.z, b.w, acc2.w);
        acc3.x = fmaf(a.w, b.x, acc3.x); acc3.y = fmaf(a.w, b.y, acc3.y);
        acc3.z = fmaf(a.w, b.z, acc3.z); acc3.w = fmaf(a.w, b.w, acc3.w);
    }
    float4* op = (float4*)(hp + (size_t)(nb + ng * 4) * FDIM + fg * 4);
    op[0] = acc0; op[32] = acc1; op[64] = acc2; op[96] = acc3;
}

// ---------------------------------------------------------------------------
// Pooling readout body (wide): 8 kept nodes per block, 256 threads=(f,half).
// ---------------------------------------------------------------------------
__device__ __forceinline__ void pool_body(const float* __restrict__ ha,
                                          const int* __restrict__ perm,
                                          const float* __restrict__ mult, int k, int pb,
                                          unsigned* __restrict__ rmax,
                                          float* __restrict__ rsum,
                                          float* __restrict__ smax,
                                          float* __restrict__ ssum) {
    const int t = threadIdx.x;
    const int g = pb & 31;
    const int c = pb >> 5;
    const int f = t & 127, half = t >> 7;
    const int base = g * k + c * 8;
    float vmax = -1e30f, vsum = 0.0f;
#pragma unroll
    for (int j0 = 0; j0 < 4; j0++) {
        int newid = base + half + j0 * 2;
        int old = perm[newid];
        float m = mult[newid];
        float v = ha[(size_t)old * FDIM + f] * m;
        vmax = fmaxf(vmax, v);
        vsum += v;
    }
    if (half) { smax[f] = vmax; ssum[f] = vsum; }
    __syncthreads();
    if (!half) {
        vmax = fmaxf(vmax, smax[f]);
        vsum += ssum[f];
        atomicMax(&rmax[g * FDIM + f], enc_f(vmax));
        atomicAdd(&rsum[g * FDIM + f], vsum);
    }
}

// ---------------------------------------------------------------------------
// Fat kernel (stage 1): direct edge binning (blocks < EBLK) | proj1.
// ---------------------------------------------------------------------------
__global__ void bin_proj1(const int* __restrict__ src, const int* __restrict__ dst,
                          int* __restrict__ cnt, int* __restrict__ slot,
                          const float* __restrict__ x, const float* __restrict__ W,
                          float* __restrict__ hp) {
    __shared__ __align__(16) float sW[4096];
    __shared__ __align__(16) float sxT[128 * SXP];
    const int t = threadIdx.x;
    if (blockIdx.x < EBLK) {
        int e = blockIdx.x * 256 + t;
        int s = src[e];
        int d = dst[e];
        int p = atomicAdd(&cnt[d], 1);
        if (p < CAP) slot[d * CAP + p] = s;
        return;
    }
    const int nb = (blockIdx.x - EBLK) * 32;
    for (int i = t; i < 4096; i += 256) sW[i] = W[i];
    for (int i = t; i < 4096; i += 256) {
        int node = i >> 7, dim = i & 127;
        sxT[dim * SXP + node] = x[(size_t)(nb + node) * FDIM + dim];
    }
    __syncthreads();
    proj_compute(hp, nb, t, sW, sxT);
}

// ---------------------------------------------------------------------------
// Fat kernel (stages 2/3): [0,EBLK) edge remap+binning over ORIGINAL edges
// with (composed) nmap | [EBLK, EBLK+ntiles) projection with perm-gathered
// input (xn never materialized) | [EBLK+ntiles, ...) PREVIOUS stage's pooling
// readout (wide; depends only on topk, same as the other two phases).
// ---------------------------------------------------------------------------
__global__ void bin_proj_pool(const int* __restrict__ src0, const int* __restrict__ dst0,
                              const int* __restrict__ nmapA, const int* __restrict__ nmapB,
                              int* __restrict__ cnt_next, int* __restrict__ slot_next,
                              const float* __restrict__ ha, const int* __restrict__ perm,
                              const float* __restrict__ mult, const float* __restrict__ W,
                              float* __restrict__ hp, int ntiles, int kprev,
                              unsigned* __restrict__ rmax, float* __restrict__ rsum) {
    __shared__ __align__(16) float sW[4096];
    __shared__ __align__(16) float sxT[128 * SXP];
    const int t = threadIdx.x;
    if (blockIdx.x < EBLK) {
        int e = blockIdx.x * 256 + t;
        int a = nmapA[src0[e]];
        int b = nmapA[dst0[e]];
        if (nmapB != nullptr) {  // wave-uniform branch
            a = (a >= 0) ? nmapB[a] : -1;
            b = (b >= 0) ? nmapB[b] : -1;
        }
        if (a >= 0 && b >= 0) {
            int p = atomicAdd(&cnt_next[b], 1);
            if (p < CAP) slot_next[b * CAP + p] = a;
        }
        return;
    }
    if (blockIdx.x >= EBLK + ntiles) {
        pool_body(ha, perm, mult, kprev, blockIdx.x - (EBLK + ntiles), rmax, rsum, sW, sW + 128);
        return;
    }
    const int nb = (blockIdx.x - EBLK) * 32;
    for (int i = t; i < 4096; i += 256) sW[i] = W[i];
    for (int i = t; i < 4096; i += 256) {
        int node = i >> 7, dim = i & 127;
        int newid = nb + node;
        sxT[dim * SXP + node] = ha[(size_t)perm[newid] * FDIM + dim] * mult[newid];
    }
    __syncthreads();
    proj_compute(hp, nb, t, sW, sxT);
}

// ---------------------------------------------------------------------------
// Standalone pooling readout (stage 3; before final_mlp).
// ---------------------------------------------------------------------------
__global__ void pool_kernel(const float* __restrict__ ha, const int* __restrict__ perm,
                            const float* __restrict__ mult, int k,
                            unsigned* __restrict__ rmax, float* __restrict__ rsum) {
    __shared__ float smax[128], ssum[128];
    pool_body(ha, perm, mult, k, blockIdx.x, rmax, rsum, smax, ssum);
}

// ---------------------------------------------------------------------------
// GCN aggregation (gather via slots) + bias + relu + fused attention score.
// Wave per node; lane = 2 features (float2); shfl-broadcast edge prefetch
// (4x unrolled). dinv on the fly from cnt. Graph->XCD swizzle: blk%32.
// ---------------------------------------------------------------------------
__global__ void agg_kernel(const float* __restrict__ hp, const float* __restrict__ b,
                           const int* __restrict__ cnt, const int* __restrict__ slot,
                           const float* __restrict__ A, const float* __restrict__ psW,
                           float* __restrict__ ha, float* __restrict__ cs, int nper) {
    const int w = threadIdx.x >> 6;
    const int lane = threadIdx.x & 63;
    const int g = blockIdx.x & 31;
    const int chunk = blockIdx.x >> 5;
    const int i = g * nper + chunk * 4 + w;
    const int ci = cnt[i];
    const float di = rsqrtf((float)ci + 1.0f);
    const int c = min(ci, CAP);
    const float2* __restrict__ hp2 = (const float2*)hp;
    float2 self = hp2[(size_t)i * 64 + lane];
    float accx = self.x * di * di, accy = self.y * di * di;
    int idx = 0;
    float dv = 0.0f;
    if (lane < c) {
        idx = slot[i * CAP + lane];
        dv = rsqrtf((float)cnt[idx] + 1.0f);
    }
    int j = 0;
    for (; j + 3 < c; j += 4) {
        int s0 = __shfl(idx, j, 64);
        int s1 = __shfl(idx, j + 1, 64);
        int s2 = __shfl(idx, j + 2, 64);
        int s3 = __shfl(idx, j + 3, 64);
        float c0 = __shfl(dv, j, 64) * di;
        float c1 = __shfl(dv, j + 1, 64) * di;
        float c2 = __shfl(dv, j + 2, 64) * di;
        float c3 = __shfl(dv, j + 3, 64) * di;
        float2 v0 = hp2[(size_t)s0 * 64 + lane];
        float2 v1 = hp2[(size_t)s1 * 64 + lane];
        float2 v2 = hp2[(size_t)s2 * 64 + lane];
        float2 v3 = hp2[(size_t)s3 * 64 + lane];
        accx = fmaf(v0.x, c0, accx); accy = fmaf(v0.y, c0, accy);
        accx = fmaf(v1.x, c1, accx); accy = fmaf(v1.y, c1, accy);
        accx = fmaf(v2.x, c2, accx); accy = fmaf(v2.y, c2, accy);
        accx = fmaf(v3.x, c3, accx); accy = fmaf(v3.y, c3, accy);
    }
    for (; j < c; j++) {
        int s = __shfl(idx, j, 64);
        float co = __shfl(dv, j, 64) * di;
        float2 v = hp2[(size_t)s * 64 + lane];
        accx = fmaf(v.x, co, accx); accy = fmaf(v.y, co, accy);
    }
    float2 bb = ((const float2*)b)[lane];
    float2 o;
    o.x = fmaxf(accx + bb.x, 0.0f);
    o.y = fmaxf(accy + bb.y, 0.0f);
    ((float2*)ha)[(size_t)i * 64 + lane] = o;
    float2 Av = ((const float2*)A)[lane];
    float2 Pv = ((const float2*)psW)[lane];
    float a = o.x * Av.x + o.y * Av.y;
    float p = o.x * Pv.x + o.y * Pv.y;
#pragma unroll
    for (int d = 8; d > 0; d >>= 1) {
        a += __shfl_down(a, d, 16);
        p += __shfl_down(p, d, 16);
    }
    float part = a * p;                  // heads at lanes 0,16,32,48
    part += __shfl_down(part, 16, 64);
    part += __shfl_down(part, 32, 64);
    if (lane == 0) cs[i] = part;
}

// ---------------------------------------------------------------------------
// Score-agg + per-graph top-k SET via 4-pass radix select (parallel digit
// selection via wave shfl suffix-scan). NO pooling here (R11 lesson: 32-block
// kernels must not carry O(k*F) gathers).
// ---------------------------------------------------------------------------
__global__ void topk_kernel(const float* __restrict__ cs, const int* __restrict__ cnt,
                            const int* __restrict__ slot, const float* __restrict__ psb,
                            int nper, int k, int* __restrict__ nmap, int* __restrict__ perm,
                            float* __restrict__ mult) {
    __shared__ float sc[NPER0];
    __shared__ unsigned ukey[NPER0];
    __shared__ unsigned hist[256];
    __shared__ unsigned wtot[4];
    __shared__ unsigned sel[2];
    __shared__ int ctr[2];
    const int g = blockIdx.x, t = threadIdx.x;
    const int w = t >> 6, l = t & 63;
    const int gnb = g * nper;
    const float pb = psb[0];
    for (int i = t; i < nper; i += 256) {
        int node = gnb + i;
        int ci = cnt[node];
        float di = rsqrtf((float)ci + 1.0f);
        float acc = cs[node] * di * di;
        int c = min(ci, CAP);
        for (int j = 0; j < c; j++) {
            int s = slot[node * CAP + j];
            acc = fmaf(cs[s], rsqrtf((float)cnt[s] + 1.0f) * di, acc);
        }
        float v = acc + pb;
        sc[i] = v;
        ukey[i] = enc_f(v);
    }
    if (t == 0) { sel[0] = 0u; sel[1] = (unsigned)k; }
    __syncthreads();
    for (int shift = 24; shift >= 0; shift -= 8) {
        hist[t] = 0u;
        __syncthreads();
        const unsigned prefix = sel[0];
        const unsigned need = sel[1];
        for (int i = t; i < nper; i += 256) {
            unsigned u = ukey[i];
            if (shift == 24 || (u >> (shift + 8)) == (prefix >> (shift + 8)))
                atomicAdd(&hist[(u >> shift) & 255], 1u);
        }
        __syncthreads();
        const unsigned h = hist[t];
        unsigned s = h;
#pragma unroll
        for (int off = 1; off < 64; off <<= 1) {
            unsigned v = __shfl_down(s, off, 64);
            if (l + off < 64) s += v;
        }
        if (l == 0) wtot[w] = s;
        __syncthreads();
        unsigned add = 0;
        for (int ww = w + 1; ww < 4; ww++) add += wtot[ww];
        const unsigned sfx = s + add;   // #keys with digit >= t (within prefix)
        const unsigned gtr = sfx - h;   // #keys with digit >  t
        if (sfx >= need && gtr < need) {  // exactly one thread
            sel[0] = prefix | ((unsigned)t << shift);
            sel[1] = need - gtr;
        }
        __syncthreads();
    }
    const unsigned T = sel[0];
    const int need = (int)sel[1];
    if (t == 0) { ctr[0] = 0; ctr[1] = k - need; }
    __syncthreads();
    for (int i = t; i < nper; i += 256) {
        unsigned u = ukey[i];
        int node = gnb + i;
        int newid = -1;
        if (u > T) {
            newid = g * k + atomicAdd(&ctr[0], 1);
        } else if (u == T) {
            int slot2 = atomicAdd(&ctr[1], 1);
            if (slot2 < k) newid = g * k + slot2;
        }
        nmap[node] = newid;
        if (newid >= 0) {
            perm[newid] = node;
            mult[newid] = tanhf(sc[i]);
        }
    }
}

// ---------------------------------------------------------------------------
// Final MLP + log_softmax. One block per graph, 128 threads.
// ---------------------------------------------------------------------------
__global__ void final_mlp(const unsigned* __restrict__ rmax, const float* __restrict__ rsum,
                          const float* __restrict__ l1W, const float* __restrict__ l1b,
                          const float* __restrict__ l2W, const float* __restrict__ l2b,
                          const float* __restrict__ l3W, const float* __restrict__ l3b,
                          float* __restrict__ out) {
    __shared__ float sz[256], s1[128], s2[64], s3[10], red[2];
    const int g = blockIdx.x, t = threadIdx.x;
    const int RS = BGR * FDIM;
    sz[t] = dec_f(rmax[g * FDIM + t]) + dec_f(rmax[RS + g * FDIM + t]) +
            dec_f(rmax[2 * RS + g * FDIM + t]);
    sz[t + 128] = rsum[g * FDIM + t] / (float)K1 + rsum[RS + g * FDIM + t] / (float)K2 +
                  rsum[2 * RS + g * FDIM + t] / (float)K3;
    __syncthreads();
    float acc = l1b[t];
    for (int i = 0; i < 256; i++) acc = fmaf(sz[i], l1W[i * 128 + t], acc);
    s1[t] = fmaxf(acc, 0.0f);
    __syncthreads();
    if (t < 64) {
        float a2 = l2b[t];
        for (int i = 0; i < 128; i++) a2 = fmaf(s1[i], l2W[i * 64 + t], a2);
        s2[t] = fmaxf(a2, 0.0f);
    }
    __syncthreads();
    if (t < 10) {
        float a3 = l3b[t];
        for (int i = 0; i < 64; i++) a3 = fmaf(s2[i], l3W[i * 10 + t], a3);
        s3[t] = a3;
    }
    __syncthreads();
    if (t == 0) {
        float m = -1e30f;
        for (int c = 0; c < 10; c++) m = fmaxf(m, s3[c]);
        float sum = 0.0f;
        for (int c = 0; c < 10; c++) sum += expf(s3[c] - m);
        red[0] = m;
        red[1] = logf(sum);
    }
    __syncthreads();
    if (t < 10) out[g * 10 + t] = s3[t] - red[0] - red[1];
}

// ---------------------------------------------------------------------------
extern "C" void kernel_launch(void* const* d_in, const int* in_sizes, int n_in,
                              void* d_out, int out_size, void* d_ws, size_t ws_size,
                              hipStream_t stream) {
    const float* x    = (const float*)d_in[0];
    const int* src0   = (const int*)d_in[1];
    const int* dst0   = (const int*)d_in[2];
    const float* W1   = (const float*)d_in[3];
    const float* b1   = (const float*)d_in[4];
    const float* A1   = (const float*)d_in[5];
    const float* ps1W = (const float*)d_in[6];
    const float* ps1b = (const float*)d_in[7];
    const float* W2   = (const float*)d_in[8];
    const float* b2   = (const float*)d_in[9];
    const float* A2   = (const float*)d_in[10];
    const float* ps2W = (const float*)d_in[11];
    const float* ps2b = (const float*)d_in[12];
    const float* W3   = (const float*)d_in[13];
    const float* b3   = (const float*)d_in[14];
    const float* A3   = (const float*)d_in[15];
    const float* ps3W = (const float*)d_in[16];
    const float* ps3b = (const float*)d_in[17];
    const float* l1W  = (const float*)d_in[18];
    const float* l1b  = (const float*)d_in[19];
    const float* l2W  = (const float*)d_in[20];
    const float* l2b  = (const float*)d_in[21];
    const float* l3W  = (const float*)d_in[22];
    const float* l3b  = (const float*)d_in[23];
    float* out = (float*)d_out;

    char* ws = (char*)d_ws;
    size_t o = 0;
    auto alloc = [&](size_t bytes) -> void* {
        void* p = ws + o;
        o += (bytes + 255) & ~(size_t)255;
        return p;
    };
    float*    hproj = (float*)alloc((size_t)N0 * FDIM * 4);
    float*    hact  = (float*)alloc((size_t)N0 * FDIM * 4);
    int*      cntA  = (int*)alloc(N0 * 4);
    int*      cntB  = (int*)alloc(BGR * K1 * 4);
    int*      cntC  = (int*)alloc(BGR * K2 * 4);
    int*      slotA = (int*)alloc((size_t)N0 * CAP * 4);
    int*      slotB = (int*)alloc((size_t)BGR * K1 * CAP * 4);
    int*      slotC = (int*)alloc((size_t)BGR * K2 * CAP * 4);
    float*    cs    = (float*)alloc(N0 * 4);
    int*      nmapA = (int*)alloc(N0 * 4);
    int*      nmapB = (int*)alloc(BGR * K1 * 4);
    int*      nmapC = (int*)alloc(BGR * K2 * 4);
    int*      perm  = (int*)alloc(BGR * K1 * 4);
    float*    mult  = (float*)alloc(BGR * K1 * 4);
    unsigned* rmax  = (unsigned*)alloc(3 * BGR * FDIM * 4);
    float*    rsum  = (float*)alloc(3 * BGR * FDIM * 4);

    const int n1 = BGR * K1, n2 = BGR * K2;
    const int RS = BGR * FDIM;

    // ---------------- Stage 1: n=32768, nper=1024, k=512 ----------------
    zero_all<<<N0 / 256, 256, 0, stream>>>(cntA, cntB, cntC, rmax, rsum);
    bin_proj1<<<EBLK + N0 / 32, 256, 0, stream>>>(src0, dst0, cntA, slotA, x, W1, hproj);
    agg_kernel<<<N0 / 4, 256, 0, stream>>>(hproj, b1, cntA, slotA, A1, ps1W, hact, cs, NPER0);
    topk_kernel<<<BGR, 256, 0, stream>>>(cs, cntA, slotA, ps1b, NPER0, K1, nmapA, perm, mult);

    // ---------------- Stage 2 (+ stage-1 pooling readout) ----------------
    bin_proj_pool<<<EBLK + n1 / 32 + BGR * K1 / 8, 256, 0, stream>>>(
        src0, dst0, nmapA, nullptr, cntB, slotB, hact, perm, mult, W2, hproj,
        n1 / 32, K1, rmax, rsum);
    agg_kernel<<<n1 / 4, 256, 0, stream>>>(hproj, b2, cntB, slotB, A2, ps2W, hact, cs, K1);
    topk_kernel<<<BGR, 256, 0, stream>>>(cs, cntB, slotB, ps2b, K1, K2, nmapB, perm, mult);

    // ---------------- Stage 3 (+ stage-2 pooling readout) ----------------
    bin_proj_pool<<<EBLK + n2 / 32 + BGR * K2 / 8, 256, 0, stream>>>(
        src0, dst0, nmapA, nmapB, cntC, slotC, hact, perm, mult, W3, hproj,
        n2 / 32, K2, rmax + RS, rsum + RS);
    agg_kernel<<<n2 / 4, 256, 0, stream>>>(hproj, b3, cntC, slotC, A3, ps3W, hact, cs, K2);
    topk_kernel<<<BGR, 256, 0, stream>>>(cs, cntC, slotC, ps3b, K2, K3, nmapC, perm, mult);

    // ---------------- Stage-3 pooling + final MLP ----------------
    pool_kernel<<<BGR * K3 / 8, 256, 0, stream>>>(hact, perm, mult, K3,
                                                  rmax + 2 * RS, rsum + 2 * RS);
    final_mlp<<<BGR, 128, 0, stream>>>(rmax, rsum, l1W, l1b, l2W, l2b, l3W, l3b, out);

    (void)in_sizes; (void)n_in; (void)out_size; (void)ws_size;
}

// Round 13
// 278.587 us; speedup vs baseline: 1.4558x; 1.0048x over previous
//
#include <hip/hip_runtime.h>
#include <math.h>

#define BGR 32
#define NPER0 1024
#define N0 (BGR * NPER0)
#define FDIM 128
#define EDG 524288
#define K1 512
#define K2 256
#define K3 128
#define EBLK (EDG / 256)  // edge-parallel blocks (2048)
#define SXP 36            // sxT row pad (floats): 16B-aligned b128 reads
#define CAP 64            // slots per node (Poisson(16); P(deg>64) ~ 1e-18)

// Order-preserving float<->uint encoding (radix keys + atomicMax readout).
__device__ __forceinline__ unsigned enc_f(float v) {
    unsigned u = __float_as_uint(v);
    return (u & 0x80000000u) ? ~u : (u | 0x80000000u);
}
__device__ __forceinline__ float dec_f(unsigned u) {
    return (u & 0x80000000u) ? __uint_as_float(u ^ 0x80000000u) : __uint_as_float(~u);
}

// ---------------------------------------------------------------------------
// Zero degree counters + atomic readout accumulators.
// ---------------------------------------------------------------------------
__global__ void zero_all(int* __restrict__ cntA, int* __restrict__ cntB,
                         int* __restrict__ cntC, unsigned* __restrict__ rmax,
                         float* __restrict__ rsum) {
    int i = blockIdx.x * 256 + threadIdx.x;
    if (i < N0) cntA[i] = 0;
    if (i < BGR * K1) cntB[i] = 0;
    if (i < BGR * K2) cntC[i] = 0;
    if (i < 3 * BGR * FDIM) { rmax[i] = 0u; rsum[i] = 0.0f; }
}

// ---------------------------------------------------------------------------
// Register-tiled projection compute: 32 nodes x 128 feats per tile;
// thread=(feature-quad, node-quad); 4x4 outer product, 2 ds_read_b128/k-step.
// ---------------------------------------------------------------------------
__device__ __forceinline__ void proj_compute(float* __restrict__ hp, int nb, int t,
                                             const float* __restrict__ sW,
                                             const float* __restrict__ sxT) {
    const int fg = t >> 3, ng = t & 7, h = fg >> 3;
    const float* ap = sxT + h * 32 * SXP + ng * 4;
    const float* bp = sW + h * 1024 + (fg & 7) * 4;
    float4 acc0 = {0.f, 0.f, 0.f, 0.f}, acc1 = acc0, acc2 = acc0, acc3 = acc0;
#pragma unroll
    for (int k = 0; k < 32; k++) {
        float4 a = *(const float4*)(ap + k * SXP);
        float4 b = *(const float4*)(bp + k * 32);
        acc0.x = fmaf(a.x, b.x, acc0.x); acc0.y = fmaf(a.x, b.y, acc0.y);
        acc0.z = fmaf(a.x, b.z, acc0.z); acc0.w = fmaf(a.x, b.w, acc0.w);
        acc1.x = fmaf(a.y, b.x, acc1.x); acc1.y = fmaf(a.y, b.y, acc1.y);
        acc1.z = fmaf(a.y, b.z, acc1.z); acc1.w = fmaf(a.y, b.w, acc1.w);
        acc2.x = fmaf(a.z, b.x, acc2.x); acc2.y = fmaf(a.z, b.y, acc2.y);
        acc2.z = fmaf(a.z, b.z, acc2.z); acc2.w = fmaf(a.z, b.w, acc2.w);
        acc3.x = fmaf(a.w, b.x, acc3.x); acc3.y = fmaf(a.w, b.y, acc3.y);
        acc3.z = fmaf(a.w, b.z, acc3.z); acc3.w = fmaf(a.w, b.w, acc3.w);
    }
    float4* op = (float4*)(hp + (size_t)(nb + ng * 4) * FDIM + fg * 4);
    op[0] = acc0; op[32] = acc1; op[64] = acc2; op[96] = acc3;
}

// ---------------------------------------------------------------------------
// Pooling readout body (wide): 8 kept nodes per block, 256 threads=(f,half).
// ---------------------------------------------------------------------------
__device__ __forceinline__ void pool_body(const float* __restrict__ ha,
                                          const int* __restrict__ perm,
                                          const float* __restrict__ mult, int k, int pb,
                                          unsigned* __restrict__ rmax,
                                          float* __restrict__ rsum,
                                          float* __restrict__ smax,
                                          float* __restrict__ ssum) {
    const int t = threadIdx.x;
    const int g = pb & 31;
    const int c = pb >> 5;
    const int f = t & 127, half = t >> 7;
    const int base = g * k + c * 8;
    float vmax = -1e30f, vsum = 0.0f;
#pragma unroll
    for (int j0 = 0; j0 < 4; j0++) {
        int newid = base + half + j0 * 2;
        int old = perm[newid];
        float m = mult[newid];
        float v = ha[(size_t)old * FDIM + f] * m;
        vmax = fmaxf(vmax, v);
        vsum += v;
    }
    if (half) { smax[f] = vmax; ssum[f] = vsum; }
    __syncthreads();
    if (!half) {
        vmax = fmaxf(vmax, smax[f]);
        vsum += ssum[f];
        atomicMax(&rmax[g * FDIM + f], enc_f(vmax));
        atomicAdd(&rsum[g * FDIM + f], vsum);
    }
}

// ---------------------------------------------------------------------------
// Fat kernel (stage 1): direct edge binning (blocks < EBLK) | proj1.
// ---------------------------------------------------------------------------
__global__ void bin_proj1(const int* __restrict__ src, const int* __restrict__ dst,
                          int* __restrict__ cnt, int* __restrict__ slot,
                          const float* __restrict__ x, const float* __restrict__ W,
                          float* __restrict__ hp) {
    __shared__ __align__(16) float sW[4096];
    __shared__ __align__(16) float sxT[128 * SXP];
    const int t = threadIdx.x;
    if (blockIdx.x < EBLK) {
        int e = blockIdx.x * 256 + t;
        int s = src[e];
        int d = dst[e];
        int p = atomicAdd(&cnt[d], 1);
        if (p < CAP) slot[d * CAP + p] = s;
        return;
    }
    const int nb = (blockIdx.x - EBLK) * 32;
    for (int i = t; i < 4096; i += 256) sW[i] = W[i];
    for (int i = t; i < 4096; i += 256) {
        int node = i >> 7, dim = i & 127;
        sxT[dim * SXP + node] = x[(size_t)(nb + node) * FDIM + dim];
    }
    __syncthreads();
    proj_compute(hp, nb, t, sW, sxT);
}

// ---------------------------------------------------------------------------
// Fat kernel (stages 2/3): [0,EBLK) edge remap+binning over ORIGINAL edges
// with (composed) nmap | [EBLK, EBLK+ntiles) projection with perm-gathered
// input (xn never materialized) | [EBLK+ntiles, ...) PREVIOUS stage's pooling
// readout (wide; depends only on topk, same as the other two phases).
// ---------------------------------------------------------------------------
__global__ void bin_proj_pool(const int* __restrict__ src0, const int* __restrict__ dst0,
                              const int* __restrict__ nmapA, const int* __restrict__ nmapB,
                              int* __restrict__ cnt_next, int* __restrict__ slot_next,
                              const float* __restrict__ ha, const int* __restrict__ perm,
                              const float* __restrict__ mult, const float* __restrict__ W,
                              float* __restrict__ hp, int ntiles, int kprev,
                              unsigned* __restrict__ rmax, float* __restrict__ rsum) {
    __shared__ __align__(16) float sW[4096];
    __shared__ __align__(16) float sxT[128 * SXP];
    const int t = threadIdx.x;
    if (blockIdx.x < EBLK) {
        int e = blockIdx.x * 256 + t;
        int a = nmapA[src0[e]];
        int b = nmapA[dst0[e]];
        if (nmapB != nullptr) {  // wave-uniform branch
            a = (a >= 0) ? nmapB[a] : -1;
            b = (b >= 0) ? nmapB[b] : -1;
        }
        if (a >= 0 && b >= 0) {
            int p = atomicAdd(&cnt_next[b], 1);
            if (p < CAP) slot_next[b * CAP + p] = a;
        }
        return;
    }
    if (blockIdx.x >= EBLK + ntiles) {
        pool_body(ha, perm, mult, kprev, blockIdx.x - (EBLK + ntiles), rmax, rsum, sW, sW + 128);
        return;
    }
    const int nb = (blockIdx.x - EBLK) * 32;
    for (int i = t; i < 4096; i += 256) sW[i] = W[i];
    for (int i = t; i < 4096; i += 256) {
        int node = i >> 7, dim = i & 127;
        int newid = nb + node;
        sxT[dim * SXP + node] = ha[(size_t)perm[newid] * FDIM + dim] * mult[newid];
    }
    __syncthreads();
    proj_compute(hp, nb, t, sW, sxT);
}

// ---------------------------------------------------------------------------
// Standalone pooling readout (stage 3; before final_mlp).
// ---------------------------------------------------------------------------
__global__ void pool_kernel(const float* __restrict__ ha, const int* __restrict__ perm,
                            const float* __restrict__ mult, int k,
                            unsigned* __restrict__ rmax, float* __restrict__ rsum) {
    __shared__ float smax[128], ssum[128];
    pool_body(ha, perm, mult, k, blockIdx.x, rmax, rsum, smax, ssum);
}

// ---------------------------------------------------------------------------
// GCN aggregation (gather via slots) + bias + relu + fused attention score.
// Wave per node; lane = 2 features (float2); shfl-broadcast edge prefetch
// (4x unrolled). dinv on the fly from cnt. Graph->XCD swizzle: blk%32.
// Writes csd[i] = cs_raw[i] * dinv[i]  (pre-scaled score -> topk's chain
// needs only ONE load per edge, no cnt/rsqrt).
// ---------------------------------------------------------------------------
__global__ void agg_kernel(const float* __restrict__ hp, const float* __restrict__ b,
                           const int* __restrict__ cnt, const int* __restrict__ slot,
                           const float* __restrict__ A, const float* __restrict__ psW,
                           float* __restrict__ ha, float* __restrict__ csd, int nper) {
    const int w = threadIdx.x >> 6;
    const int lane = threadIdx.x & 63;
    const int g = blockIdx.x & 31;
    const int chunk = blockIdx.x >> 5;
    const int i = g * nper + chunk * 4 + w;
    const int ci = cnt[i];
    const float di = rsqrtf((float)ci + 1.0f);
    const int c = min(ci, CAP);
    const float2* __restrict__ hp2 = (const float2*)hp;
    float2 self = hp2[(size_t)i * 64 + lane];
    float accx = self.x * di * di, accy = self.y * di * di;
    int idx = 0;
    float dv = 0.0f;
    if (lane < c) {
        idx = slot[i * CAP + lane];
        dv = rsqrtf((float)cnt[idx] + 1.0f);
    }
    int j = 0;
    for (; j + 3 < c; j += 4) {
        int s0 = __shfl(idx, j, 64);
        int s1 = __shfl(idx, j + 1, 64);
        int s2 = __shfl(idx, j + 2, 64);
        int s3 = __shfl(idx, j + 3, 64);
        float c0 = __shfl(dv, j, 64) * di;
        float c1 = __shfl(dv, j + 1, 64) * di;
        float c2 = __shfl(dv, j + 2, 64) * di;
        float c3 = __shfl(dv, j + 3, 64) * di;
        float2 v0 = hp2[(size_t)s0 * 64 + lane];
        float2 v1 = hp2[(size_t)s1 * 64 + lane];
        float2 v2 = hp2[(size_t)s2 * 64 + lane];
        float2 v3 = hp2[(size_t)s3 * 64 + lane];
        accx = fmaf(v0.x, c0, accx); accy = fmaf(v0.y, c0, accy);
        accx = fmaf(v1.x, c1, accx); accy = fmaf(v1.y, c1, accy);
        accx = fmaf(v2.x, c2, accx); accy = fmaf(v2.y, c2, accy);
        accx = fmaf(v3.x, c3, accx); accy = fmaf(v3.y, c3, accy);
    }
    for (; j < c; j++) {
        int s = __shfl(idx, j, 64);
        float co = __shfl(dv, j, 64) * di;
        float2 v = hp2[(size_t)s * 64 + lane];
        accx = fmaf(v.x, co, accx); accy = fmaf(v.y, co, accy);
    }
    float2 bb = ((const float2*)b)[lane];
    float2 o;
    o.x = fmaxf(accx + bb.x, 0.0f);
    o.y = fmaxf(accy + bb.y, 0.0f);
    ((float2*)ha)[(size_t)i * 64 + lane] = o;
    float2 Av = ((const float2*)A)[lane];
    float2 Pv = ((const float2*)psW)[lane];
    float a = o.x * Av.x + o.y * Av.y;
    float p = o.x * Pv.x + o.y * Pv.y;
#pragma unroll
    for (int d = 8; d > 0; d >>= 1) {
        a += __shfl_down(a, d, 16);
        p += __shfl_down(p, d, 16);
    }
    float part = a * p;                  // heads at lanes 0,16,32,48
    part += __shfl_down(part, 16, 64);
    part += __shfl_down(part, 32, 64);
    if (lane == 0) csd[i] = part * di;   // pre-scaled by dinv[i]
}

// ---------------------------------------------------------------------------
// Score-agg + per-graph top-k SET via 4-pass radix select.
// Score phase: v = di*(sum_j csd[slot_j] + csd[i]) + pb, with the thread's
// Q=nper/256 nodes processed INTERLEAVED in the j-loop -> 4 independent
// slot->csd chains in flight (was 1; 32-block kernel has no TLP to hide
// the serial chain otherwise).
// ---------------------------------------------------------------------------
__global__ void topk_kernel(const float* __restrict__ csd, const int* __restrict__ cnt,
                            const int* __restrict__ slot, const float* __restrict__ psb,
                            int nper, int k, int* __restrict__ nmap, int* __restrict__ perm,
                            float* __restrict__ mult) {
    __shared__ float sc[NPER0];
    __shared__ unsigned ukey[NPER0];
    __shared__ unsigned hist[256];
    __shared__ unsigned wtot[4];
    __shared__ unsigned sel[2];
    __shared__ int ctr[2];
    const int g = blockIdx.x, t = threadIdx.x;
    const int w = t >> 6, l = t & 63;
    const int gnb = g * nper;
    const float pb = psb[0];
    const int Q = nper >> 8;  // 4, 2, or 1 nodes per thread
    {
        float acc[4] = {0.f, 0.f, 0.f, 0.f};
        float selfc[4] = {0.f, 0.f, 0.f, 0.f};
        float dl[4] = {0.f, 0.f, 0.f, 0.f};
        int nd[4] = {0, 0, 0, 0};
        int cc[4] = {0, 0, 0, 0};
        int m = 0;
#pragma unroll
        for (int q = 0; q < 4; q++) {
            if (q < Q) {
                int node = gnb + t + q * 256;
                int ci = cnt[node];
                nd[q] = node;
                cc[q] = min(ci, CAP);
                dl[q] = rsqrtf((float)ci + 1.0f);
                selfc[q] = csd[node];
                m = max(m, cc[q]);
            }
        }
        for (int j = 0; j < m; j++) {
#pragma unroll
            for (int q = 0; q < 4; q++) {
                if (q < Q && j < cc[q]) {
                    int s = slot[nd[q] * CAP + j];
                    acc[q] += csd[s];
                }
            }
        }
#pragma unroll
        for (int q = 0; q < 4; q++) {
            if (q < Q) {
                float v = dl[q] * (acc[q] + selfc[q]) + pb;
                sc[t + q * 256] = v;
                ukey[t + q * 256] = enc_f(v);
            }
        }
    }
    if (t == 0) { sel[0] = 0u; sel[1] = (unsigned)k; }
    __syncthreads();
    for (int shift = 24; shift >= 0; shift -= 8) {
        hist[t] = 0u;
        __syncthreads();
        const unsigned prefix = sel[0];
        const unsigned need = sel[1];
        for (int i = t; i < nper; i += 256) {
            unsigned u = ukey[i];
            if (shift == 24 || (u >> (shift + 8)) == (prefix >> (shift + 8)))
                atomicAdd(&hist[(u >> shift) & 255], 1u);
        }
        __syncthreads();
        const unsigned h = hist[t];
        unsigned s = h;
#pragma unroll
        for (int off = 1; off < 64; off <<= 1) {
            unsigned v = __shfl_down(s, off, 64);
            if (l + off < 64) s += v;
        }
        if (l == 0) wtot[w] = s;
        __syncthreads();
        unsigned add = 0;
        for (int ww = w + 1; ww < 4; ww++) add += wtot[ww];
        const unsigned sfx = s + add;   // #keys with digit >= t (within prefix)
        const unsigned gtr = sfx - h;   // #keys with digit >  t
        if (sfx >= need && gtr < need) {  // exactly one thread
            sel[0] = prefix | ((unsigned)t << shift);
            sel[1] = need - gtr;
        }
        __syncthreads();
    }
    const unsigned T = sel[0];
    const int need = (int)sel[1];
    if (t == 0) { ctr[0] = 0; ctr[1] = k - need; }
    __syncthreads();
    for (int i = t; i < nper; i += 256) {
        unsigned u = ukey[i];
        int node = gnb + i;
        int newid = -1;
        if (u > T) {
            newid = g * k + atomicAdd(&ctr[0], 1);
        } else if (u == T) {
            int slot2 = atomicAdd(&ctr[1], 1);
            if (slot2 < k) newid = g * k + slot2;
        }
        nmap[node] = newid;
        if (newid >= 0) {
            perm[newid] = node;
            mult[newid] = tanhf(sc[i]);
        }
    }
}

// ---------------------------------------------------------------------------
// Final MLP + log_softmax. One block per graph, 128 threads.
// ---------------------------------------------------------------------------
__global__ void final_mlp(const unsigned* __restrict__ rmax, const float* __restrict__ rsum,
                          const float* __restrict__ l1W, const float* __restrict__ l1b,
                          const float* __restrict__ l2W, const float* __restrict__ l2b,
                          const float* __restrict__ l3W, const float* __restrict__ l3b,
                          float* __restrict__ out) {
    __shared__ float sz[256], s1[128], s2[64], s3[10], red[2];
    const int g = blockIdx.x, t = threadIdx.x;
    const int RS = BGR * FDIM;
    sz[t] = dec_f(rmax[g * FDIM + t]) + dec_f(rmax[RS + g * FDIM + t]) +
            dec_f(rmax[2 * RS + g * FDIM + t]);
    sz[t + 128] = rsum[g * FDIM + t] / (float)K1 + rsum[RS + g * FDIM + t] / (float)K2 +
                  rsum[2 * RS + g * FDIM + t] / (float)K3;
    __syncthreads();
    float acc = l1b[t];
    for (int i = 0; i < 256; i++) acc = fmaf(sz[i], l1W[i * 128 + t], acc);
    s1[t] = fmaxf(acc, 0.0f);
    __syncthreads();
    if (t < 64) {
        float a2 = l2b[t];
        for (int i = 0; i < 128; i++) a2 = fmaf(s1[i], l2W[i * 64 + t], a2);
        s2[t] = fmaxf(a2, 0.0f);
    }
    __syncthreads();
    if (t < 10) {
        float a3 = l3b[t];
        for (int i = 0; i < 64; i++) a3 = fmaf(s2[i], l3W[i * 10 + t], a3);
        s3[t] = a3;
    }
    __syncthreads();
    if (t == 0) {
        float m = -1e30f;
        for (int c = 0; c < 10; c++) m = fmaxf(m, s3[c]);
        float sum = 0.0f;
        for (int c = 0; c < 10; c++) sum += expf(s3[c] - m);
        red[0] = m;
        red[1] = logf(sum);
    }
    __syncthreads();
    if (t < 10) out[g * 10 + t] = s3[t] - red[0] - red[1];
}

// ---------------------------------------------------------------------------
extern "C" void kernel_launch(void* const* d_in, const int* in_sizes, int n_in,
                              void* d_out, int out_size, void* d_ws, size_t ws_size,
                              hipStream_t stream) {
    const float* x    = (const float*)d_in[0];
    const int* src0   = (const int*)d_in[1];
    const int* dst0   = (const int*)d_in[2];
    const float* W1   = (const float*)d_in[3];
    const float* b1   = (const float*)d_in[4];
    const float* A1   = (const float*)d_in[5];
    const float* ps1W = (const float*)d_in[6];
    const float* ps1b = (const float*)d_in[7];
    const float* W2   = (const float*)d_in[8];
    const float* b2   = (const float*)d_in[9];
    const float* A2   = (const float*)d_in[10];
    const float* ps2W = (const float*)d_in[11];
    const float* ps2b = (const float*)d_in[12];
    const float* W3   = (const float*)d_in[13];
    const float* b3   = (const float*)d_in[14];
    const float* A3   = (const float*)d_in[15];
    const float* ps3W = (const float*)d_in[16];
    const float* ps3b = (const float*)d_in[17];
    const float* l1W  = (const float*)d_in[18];
    const float* l1b  = (const float*)d_in[19];
    const float* l2W  = (const float*)d_in[20];
    const float* l2b  = (const float*)d_in[21];
    const float* l3W  = (const float*)d_in[22];
    const float* l3b  = (const float*)d_in[23];
    float* out = (float*)d_out;

    char* ws = (char*)d_ws;
    size_t o = 0;
    auto alloc = [&](size_t bytes) -> void* {
        void* p = ws + o;
        o += (bytes + 255) & ~(size_t)255;
        return p;
    };
    float*    hproj = (float*)alloc((size_t)N0 * FDIM * 4);
    float*    hact  = (float*)alloc((size_t)N0 * FDIM * 4);
    int*      cntA  = (int*)alloc(N0 * 4);
    int*      cntB  = (int*)alloc(BGR * K1 * 4);
    int*      cntC  = (int*)alloc(BGR * K2 * 4);
    int*      slotA = (int*)alloc((size_t)N0 * CAP * 4);
    int*      slotB = (int*)alloc((size_t)BGR * K1 * CAP * 4);
    int*      slotC = (int*)alloc((size_t)BGR * K2 * CAP * 4);
    float*    cs    = (float*)alloc(N0 * 4);
    int*      nmapA = (int*)alloc(N0 * 4);
    int*      nmapB = (int*)alloc(BGR * K1 * 4);
    int*      nmapC = (int*)alloc(BGR * K2 * 4);
    int*      perm  = (int*)alloc(BGR * K1 * 4);
    float*    mult  = (float*)alloc(BGR * K1 * 4);
    unsigned* rmax  = (unsigned*)alloc(3 * BGR * FDIM * 4);
    float*    rsum  = (float*)alloc(3 * BGR * FDIM * 4);

    const int n1 = BGR * K1, n2 = BGR * K2;
    const int RS = BGR * FDIM;

    // ---------------- Stage 1: n=32768, nper=1024, k=512 ----------------
    zero_all<<<N0 / 256, 256, 0, stream>>>(cntA, cntB, cntC, rmax, rsum);
    bin_proj1<<<EBLK + N0 / 32, 256, 0, stream>>>(src0, dst0, cntA, slotA, x, W1, hproj);
    agg_kernel<<<N0 / 4, 256, 0, stream>>>(hproj, b1, cntA, slotA, A1, ps1W, hact, cs, NPER0);
    topk_kernel<<<BGR, 256, 0, stream>>>(cs, cntA, slotA, ps1b, NPER0, K1, nmapA, perm, mult);

    // ---------------- Stage 2 (+ stage-1 pooling readout) ----------------
    bin_proj_pool<<<EBLK + n1 / 32 + BGR * K1 / 8, 256, 0, stream>>>(
        src0, dst0, nmapA, nullptr, cntB, slotB, hact, perm, mult, W2, hproj,
        n1 / 32, K1, rmax, rsum);
    agg_kernel<<<n1 / 4, 256, 0, stream>>>(hproj, b2, cntB, slotB, A2, ps2W, hact, cs, K1);
    topk_kernel<<<BGR, 256, 0, stream>>>(cs, cntB, slotB, ps2b, K1, K2, nmapB, perm, mult);

    // ---------------- Stage 3 (+ stage-2 pooling readout) ----------------
    bin_proj_pool<<<EBLK + n2 / 32 + BGR * K2 / 8, 256, 0, stream>>>(
        src0, dst0, nmapA, nmapB, cntC, slotC, hact, perm, mult, W3, hproj,
        n2 / 32, K2, rmax + RS, rsum + RS);
    agg_kernel<<<n2 / 4, 256, 0, stream>>>(hproj, b3, cntC, slotC, A3, ps3W, hact, cs, K2);
    topk_kernel<<<BGR, 256, 0, stream>>>(cs, cntC, slotC, ps3b, K2, K3, nmapC, perm, mult);

    // ---------------- Stage-3 pooling + final MLP ----------------
    pool_kernel<<<BGR * K3 / 8, 256, 0, stream>>>(hact, perm, mult, K3,
                                                  rmax + 2 * RS, rsum + 2 * RS);
    final_mlp<<<BGR, 128, 0, stream>>>(rmax, rsum, l1W, l1b, l2W, l2b, l3W, l3b, out);

    (void)in_sizes; (void)n_in; (void)out_size; (void)ws_size;
}